// Round 1
// baseline (9402.898 us; speedup 1.0000x reference)
//
#include <hip/hip_runtime.h>

#define H 128
#define FN 16
#define FE 8

// ---------------- K1: edge-attr embed + scatter-add to dst nodes ----------------
// agg[dst[e]] += edge_attr[e] @ W_edge     (atomics)
__global__ __launch_bounds__(256) void k_embed_scatter(
    const float* __restrict__ edge_attr, const int* __restrict__ dst_idx,
    const float* __restrict__ W_edge, float* __restrict__ agg, int E) {
  __shared__ float We[FE * H];     // 4 KB
  __shared__ float ea[2][FE];
  for (int i = threadIdx.x; i < FE * H; i += 256) We[i] = W_edge[i];
  int lane = threadIdx.x & 127;    // feature
  int sub  = threadIdx.x >> 7;     // which edge in the pair
  for (int e0 = blockIdx.x * 2; e0 < E; e0 += gridDim.x * 2) {
    int e = e0 + sub;
    __syncthreads();               // protect ea reuse across iterations (and We on iter 0)
    if (e < E && lane < FE) ea[sub][lane] = edge_attr[(size_t)e * FE + lane];
    __syncthreads();
    if (e < E) {
      float acc = 0.f;
#pragma unroll
      for (int k = 0; k < FE; k++) acc += ea[sub][k] * We[k * H + lane];
      int d = dst_idx[e];
      atomicAdd(&agg[(size_t)d * H + lane], acc);
    }
  }
}

// ---------------- K2: h = relu(node_attr @ W_node + agg + b_embed) ----------------
__global__ __launch_bounds__(256) void k_embed_h(
    const float* __restrict__ node_attr, const float* __restrict__ Wn,
    const float* __restrict__ b, const float* __restrict__ agg,
    float* __restrict__ h, int N) {
  __shared__ float Ws[FN * H];     // 8 KB
  __shared__ float na[2][FN];
  for (int i = threadIdx.x; i < FN * H; i += 256) Ws[i] = Wn[i];
  int lane = threadIdx.x & 127;
  int sub  = threadIdx.x >> 7;
  for (int n0 = blockIdx.x * 2; n0 < N; n0 += gridDim.x * 2) {
    int n = n0 + sub;
    __syncthreads();
    if (n < N && lane < FN) na[sub][lane] = node_attr[(size_t)n * FN + lane];
    __syncthreads();
    if (n < N) {
      float acc = b[lane] + agg[(size_t)n * H + lane];
#pragma unroll
      for (int k = 0; k < FN; k++) acc += na[sub][k] * Ws[k * H + lane];
      h[(size_t)n * H + lane] = fmaxf(acc, 0.f);
    }
  }
}

// ---------------- K3: out[N,H] = act(in)[N,H] @ W[H,H] + bias ----------------
// Block: 256 thr, tile 64 rows x 128 cols, k-chunks of 32 staged in LDS.
// Thread (c = tid&31, rg = tid>>5): 4 cols [4c..4c+3] x 8 rows (rg + 8i). FMA-bound.
template <int RELU_IN>
__global__ __launch_bounds__(256) void k_gemm(
    const float* __restrict__ in, const float* __restrict__ W,
    const float* __restrict__ bias, float* __restrict__ out, int N) {
  __shared__ float Ws[32 * H];   // 16 KB
  __shared__ float hs[64 * 32];  // 8 KB
  int tid = threadIdx.x;
  int c = tid & 31;
  int rg = tid >> 5;
  int rowBase = blockIdx.x * 64;
  float4 acc[8];
#pragma unroll
  for (int i = 0; i < 8; i++) acc[i] = make_float4(0.f, 0.f, 0.f, 0.f);

  float4* Ws4 = (float4*)Ws;
  float4* hs4 = (float4*)hs;
  for (int kk = 0; kk < 4; kk++) {
    const float4* Wg = (const float4*)(W + (size_t)kk * 32 * H);
#pragma unroll
    for (int p = 0; p < 4; p++) Ws4[tid + 256 * p] = Wg[tid + 256 * p];
#pragma unroll
    for (int p = 0; p < 2; p++) {
      int q = tid + 256 * p;           // 0..511 float4 slots
      int r = q >> 3, kq = q & 7;
      int row = rowBase + r;
      float4 v = make_float4(0.f, 0.f, 0.f, 0.f);
      if (row < N) v = ((const float4*)(in + (size_t)row * H + kk * 32))[kq];
      if (RELU_IN) {
        v.x = fmaxf(v.x, 0.f); v.y = fmaxf(v.y, 0.f);
        v.z = fmaxf(v.z, 0.f); v.w = fmaxf(v.w, 0.f);
      }
      hs4[q] = v;
    }
    __syncthreads();
#pragma unroll
    for (int k4 = 0; k4 < 8; k4++) {
      float4 w0 = Ws4[(k4 * 4 + 0) * 32 + c];
      float4 w1 = Ws4[(k4 * 4 + 1) * 32 + c];
      float4 w2 = Ws4[(k4 * 4 + 2) * 32 + c];
      float4 w3 = Ws4[(k4 * 4 + 3) * 32 + c];
#pragma unroll
      for (int i = 0; i < 8; i++) {
        float4 hv = hs4[(rg + 8 * i) * 8 + k4];
        acc[i].x += hv.x * w0.x + hv.y * w1.x + hv.z * w2.x + hv.w * w3.x;
        acc[i].y += hv.x * w0.y + hv.y * w1.y + hv.z * w2.y + hv.w * w3.y;
        acc[i].z += hv.x * w0.z + hv.y * w1.z + hv.z * w2.z + hv.w * w3.z;
        acc[i].w += hv.x * w0.w + hv.y * w1.w + hv.z * w2.w + hv.w * w3.w;
      }
    }
    __syncthreads();
  }
  float4 bv = ((const float4*)bias)[c];
#pragma unroll
  for (int i = 0; i < 8; i++) {
    int row = rowBase + rg + 8 * i;
    if (row < N) {
      float4 o = make_float4(acc[i].x + bv.x, acc[i].y + bv.y,
                             acc[i].z + bv.z, acc[i].w + bv.w);
      ((float4*)(out + (size_t)row * H))[c] = o;
    }
  }
}

// ---------------- K4: agg[src[e]] += val[e] * hw[dst[e]]  (atomics) ----------------
__global__ __launch_bounds__(256) void k_gcn_scatter(
    const float* __restrict__ hw, const int* __restrict__ src_idx,
    const int* __restrict__ dst_idx, const float* __restrict__ val,
    float* __restrict__ agg, int E) {
  int e = blockIdx.x * 8 + (threadIdx.x >> 5);
  if (e >= E) return;
  int c = threadIdx.x & 31;
  int s = src_idx[e], d = dst_idx[e];
  float v = val[e];
  float4 hv = ((const float4*)(hw + (size_t)d * H))[c];
  float* ap = agg + (size_t)s * H + c * 4;
  atomicAdd(ap + 0, v * hv.x);
  atomicAdd(ap + 1, v * hv.y);
  atomicAdd(ap + 2, v * hv.z);
  atomicAdd(ap + 3, v * hv.w);
}

// ---------------- K5: fp[batch[n]] += relu(h[n])  (atomics) ----------------
__global__ __launch_bounds__(256) void k_pool(
    const float* __restrict__ h, const int* __restrict__ batch,
    float* __restrict__ fp, int N) {
  int n = blockIdx.x * 8 + (threadIdx.x >> 5);
  if (n >= N) return;
  int c = threadIdx.x & 31;
  int g = batch[n];
  float4 hv = ((const float4*)(h + (size_t)n * H))[c];
  float* p = fp + (size_t)g * H + c * 4;
  atomicAdd(p + 0, fmaxf(hv.x, 0.f));
  atomicAdd(p + 1, fmaxf(hv.y, 0.f));
  atomicAdd(p + 2, fmaxf(hv.z, 0.f));
  atomicAdd(p + 3, fmaxf(hv.w, 0.f));
}

// ---------------- K6: out[g] = relu(fp[g]@Wp1 + bp1) @ Wp2 + bp2 ----------------
__global__ __launch_bounds__(128) void k_pred(
    const float* __restrict__ fp, const float* __restrict__ Wp1,
    const float* __restrict__ bp1, const float* __restrict__ Wp2,
    const float* __restrict__ bp2, float* __restrict__ out, int G) {
  __shared__ float fs[H];
  __shared__ float partial[2];
  int g = blockIdx.x;
  int j = threadIdx.x;
  fs[j] = fp[(size_t)g * H + j];
  __syncthreads();
  float acc = bp1[j];
#pragma unroll 4
  for (int k = 0; k < H; k++) acc += fs[k] * Wp1[(size_t)k * H + j];
  float z = fmaxf(acc, 0.f) * Wp2[j];
#pragma unroll
  for (int off = 32; off > 0; off >>= 1) z += __shfl_down(z, off, 64);
  if ((j & 63) == 0) partial[j >> 6] = z;
  __syncthreads();
  if (j == 0) out[g] = partial[0] + partial[1] + bp2[0];
}

extern "C" void kernel_launch(void* const* d_in, const int* in_sizes, int n_in,
                              void* d_out, int out_size, void* d_ws, size_t ws_size,
                              hipStream_t stream) {
  const float* node_attr = (const float*)d_in[0];
  const float* edge_attr = (const float*)d_in[1];
  const int*   edge_index = (const int*)d_in[2];
  const int*   adj_index  = (const int*)d_in[3];
  const float* adj_value  = (const float*)d_in[4];
  const int*   batch      = (const int*)d_in[5];
  const float* W_node  = (const float*)d_in[6];
  const float* W_edge  = (const float*)d_in[7];
  const float* b_embed = (const float*)d_in[8];
  const float* W1 = (const float*)d_in[9];
  const float* b1 = (const float*)d_in[10];
  const float* W2 = (const float*)d_in[11];
  const float* b2 = (const float*)d_in[12];
  const float* W3 = (const float*)d_in[13];
  const float* b3 = (const float*)d_in[14];
  const float* Wp1 = (const float*)d_in[15];
  const float* bp1 = (const float*)d_in[16];
  const float* Wp2 = (const float*)d_in[17];
  const float* bp2 = (const float*)d_in[18];
  float* out = (float*)d_out;

  const int E = in_sizes[4];   // 1,600,000
  const int N = in_sizes[5];   // 100,000
  const int G = out_size;      // 2048

  float* A  = (float*)d_ws;                 // N*H
  float* B  = A + (size_t)N * H;            // N*H
  float* fp = B + (size_t)N * H;            // G*H
  size_t nh_bytes = (size_t)N * H * sizeof(float);

  int gemm_blocks    = (N + 63) / 64;
  int scatter_blocks = (E + 7) / 8;

  // embed
  hipMemsetAsync(A, 0, nh_bytes, stream);
  k_embed_scatter<<<4096, 256, 0, stream>>>(edge_attr, edge_index + E, W_edge, A, E);
  k_embed_h<<<4096, 256, 0, stream>>>(node_attr, W_node, b_embed, A, B, N);

  // GCN layer 1:  A = B@W1+b1 ; B = scatter(adj, A)
  k_gemm<0><<<gemm_blocks, 256, 0, stream>>>(B, W1, b1, A, N);
  hipMemsetAsync(B, 0, nh_bytes, stream);
  k_gcn_scatter<<<scatter_blocks, 256, 0, stream>>>(A, adj_index, adj_index + E, adj_value, B, E);

  // GCN layer 2
  k_gemm<1><<<gemm_blocks, 256, 0, stream>>>(B, W2, b2, A, N);
  hipMemsetAsync(B, 0, nh_bytes, stream);
  k_gcn_scatter<<<scatter_blocks, 256, 0, stream>>>(A, adj_index, adj_index + E, adj_value, B, E);

  // GCN layer 3
  k_gemm<1><<<gemm_blocks, 256, 0, stream>>>(B, W3, b3, A, N);
  hipMemsetAsync(B, 0, nh_bytes, stream);
  k_gcn_scatter<<<scatter_blocks, 256, 0, stream>>>(A, adj_index, adj_index + E, adj_value, B, E);

  // pool (relu folded in) + predictor
  hipMemsetAsync(fp, 0, (size_t)G * H * sizeof(float), stream);
  k_pool<<<(N + 7) / 8, 256, 0, stream>>>(B, batch, fp, N);
  k_pred<<<G, 128, 0, stream>>>(fp, Wp1, bp1, Wp2, bp2, out, G);
}

// Round 2
// 1327.044 us; speedup vs baseline: 7.0856x; 7.0856x over previous
//
#include <hip/hip_runtime.h>

#define H 128
#define FN 16
#define FE 8

// ============================ counting-sort kernels ============================
// Build CSR: offsets[n] = start of node n's edge segment; payload permuted.

__global__ __launch_bounds__(256) void k_hist(
    const int* __restrict__ key, int* __restrict__ cnt, int E) {
  int e = blockIdx.x * 256 + threadIdx.x;
  if (e < E) atomicAdd(&cnt[key[e]], 1);
}

// pass 1: per-block (1024 elems) sums
__global__ __launch_bounds__(256) void k_scan1(
    const int* __restrict__ cnt, int* __restrict__ bsum, int N) {
  __shared__ int s[256];
  int base = blockIdx.x * 1024 + threadIdx.x * 4;
  int t = 0;
#pragma unroll
  for (int j = 0; j < 4; j++) { int i = base + j; if (i < N) t += cnt[i]; }
  s[threadIdx.x] = t; __syncthreads();
  for (int off = 128; off > 0; off >>= 1) {
    if (threadIdx.x < off) s[threadIdx.x] += s[threadIdx.x + off];
    __syncthreads();
  }
  if (threadIdx.x == 0) bsum[blockIdx.x] = s[0];
}

// pass 2: single block scans block sums (NB <= 128); writes offs[N] = total
__global__ __launch_bounds__(128) void k_scan2(
    const int* __restrict__ bsum, int* __restrict__ bsumEx,
    int* __restrict__ offs, int NB, int N) {
  __shared__ int s[128];
  int tid = threadIdx.x;
  int v = (tid < NB) ? bsum[tid] : 0;
  s[tid] = v; __syncthreads();
  for (int off = 1; off < 128; off <<= 1) {
    int t = 0;
    if (tid >= off) t = s[tid - off];
    __syncthreads();
    if (tid >= off) s[tid] += t;
    __syncthreads();
  }
  if (tid < NB) bsumEx[tid] = s[tid] - v;   // exclusive
  if (tid == 127) offs[N] = s[127];         // grand total (=E)
}

// pass 3: per-block exclusive scan + block offset -> offsets
__global__ __launch_bounds__(256) void k_scan3(
    const int* __restrict__ cnt, const int* __restrict__ bsumEx,
    int* __restrict__ offs, int N) {
  __shared__ int s[256];
  int tid = threadIdx.x;
  int base = blockIdx.x * 1024 + tid * 4;
  int c[4]; int t = 0;
#pragma unroll
  for (int j = 0; j < 4; j++) { int i = base + j; c[j] = (i < N) ? cnt[i] : 0; t += c[j]; }
  s[tid] = t; __syncthreads();
  for (int off = 1; off < 256; off <<= 1) {
    int u = 0;
    if (tid >= off) u = s[tid - off];
    __syncthreads();
    if (tid >= off) s[tid] += u;
    __syncthreads();
  }
  int ex = s[tid] - t + bsumEx[blockIdx.x];
#pragma unroll
  for (int j = 0; j < 4; j++) {
    int i = base + j;
    if (i < N) offs[i] = ex;
    ex += c[j];
  }
}

// scatter permutation: edge-id payload (for embed: index into edge_attr)
__global__ __launch_bounds__(256) void k_scatter_idx(
    const int* __restrict__ key, int* __restrict__ cursor,
    int* __restrict__ perm, int E) {
  int e = blockIdx.x * 256 + threadIdx.x;
  if (e < E) { int p = atomicAdd(&cursor[key[e]], 1); perm[p] = e; }
}

// scatter permutation: (dst, val) payload directly (for GCN layers)
__global__ __launch_bounds__(256) void k_scatter_pay(
    const int* __restrict__ key, const int* __restrict__ dst,
    const float* __restrict__ val, int* __restrict__ cursor,
    int* __restrict__ dstP, float* __restrict__ valP, int E) {
  int e = blockIdx.x * 256 + threadIdx.x;
  if (e < E) {
    int p = atomicAdd(&cursor[key[e]], 1);
    dstP[p] = dst[e];
    valP[p] = val[e];
  }
}

// ============================ embed stage ============================
// agg8[n] = sum_{e: dst(e)=n} edge_attr[e]   (8 floats; W_edge folded later)
__global__ __launch_bounds__(256) void k_embed_gather(
    const float* __restrict__ edge_attr, const int* __restrict__ offs,
    const int* __restrict__ perm, float* __restrict__ agg8, int N) {
  int n = blockIdx.x * 32 + (threadIdx.x >> 3);
  if (n >= N) return;
  int c = threadIdx.x & 7;
  int s = offs[n], t = offs[n + 1];
  float acc = 0.f;
  for (int i = s; i < t; i++) {
    int e = perm[i];
    acc += edge_attr[(size_t)e * FE + c];
  }
  agg8[(size_t)n * FE + c] = acc;
}

// h = relu(node_attr @ W_node + agg8 @ W_edge + b_embed)
__global__ __launch_bounds__(256) void k_embed_h(
    const float* __restrict__ node_attr, const float* __restrict__ Wn,
    const float* __restrict__ We8, const float* __restrict__ b,
    const float* __restrict__ agg8, float* __restrict__ h, int N) {
  __shared__ float Ws[FN * H];   // 8 KB
  __shared__ float Es[FE * H];   // 4 KB
  __shared__ float na[2][FN];
  __shared__ float a8[2][FE];
  for (int i = threadIdx.x; i < FN * H; i += 256) Ws[i] = Wn[i];
  for (int i = threadIdx.x; i < FE * H; i += 256) Es[i] = We8[i];
  int lane = threadIdx.x & 127;
  int sub  = threadIdx.x >> 7;
  for (int n0 = blockIdx.x * 2; n0 < N; n0 += gridDim.x * 2) {
    int n = n0 + sub;
    __syncthreads();
    if (n < N) {
      if (lane < FN) na[sub][lane] = node_attr[(size_t)n * FN + lane];
      else if (lane < FN + FE) a8[sub][lane - FN] = agg8[(size_t)n * FE + (lane - FN)];
    }
    __syncthreads();
    if (n < N) {
      float acc = b[lane];
#pragma unroll
      for (int k = 0; k < FN; k++) acc += na[sub][k] * Ws[k * H + lane];
#pragma unroll
      for (int k = 0; k < FE; k++) acc += a8[sub][k] * Es[k * H + lane];
      h[(size_t)n * H + lane] = fmaxf(acc, 0.f);
    }
  }
}

// ============================ dense GEMM [N,H]@[H,H]+b ============================
__global__ __launch_bounds__(256) void k_gemm(
    const float* __restrict__ in, const float* __restrict__ W,
    const float* __restrict__ bias, float* __restrict__ out, int N) {
  __shared__ float Ws[32 * H];   // 16 KB
  __shared__ float hs[64 * 32];  // 8 KB
  int tid = threadIdx.x;
  int c = tid & 31;
  int rg = tid >> 5;
  int rowBase = blockIdx.x * 64;
  float4 acc[8];
#pragma unroll
  for (int i = 0; i < 8; i++) acc[i] = make_float4(0.f, 0.f, 0.f, 0.f);

  float4* Ws4 = (float4*)Ws;
  float4* hs4 = (float4*)hs;
  for (int kk = 0; kk < 4; kk++) {
    const float4* Wg = (const float4*)(W + (size_t)kk * 32 * H);
#pragma unroll
    for (int p = 0; p < 4; p++) Ws4[tid + 256 * p] = Wg[tid + 256 * p];
#pragma unroll
    for (int p = 0; p < 2; p++) {
      int q = tid + 256 * p;
      int r = q >> 3, kq = q & 7;
      int row = rowBase + r;
      float4 v = make_float4(0.f, 0.f, 0.f, 0.f);
      if (row < N) v = ((const float4*)(in + (size_t)row * H + kk * 32))[kq];
      hs4[q] = v;
    }
    __syncthreads();
#pragma unroll
    for (int k4 = 0; k4 < 8; k4++) {
      float4 w0 = Ws4[(k4 * 4 + 0) * 32 + c];
      float4 w1 = Ws4[(k4 * 4 + 1) * 32 + c];
      float4 w2 = Ws4[(k4 * 4 + 2) * 32 + c];
      float4 w3 = Ws4[(k4 * 4 + 3) * 32 + c];
#pragma unroll
      for (int i = 0; i < 8; i++) {
        float4 hv = hs4[(rg + 8 * i) * 8 + k4];
        acc[i].x += hv.x * w0.x + hv.y * w1.x + hv.z * w2.x + hv.w * w3.x;
        acc[i].y += hv.x * w0.y + hv.y * w1.y + hv.z * w2.y + hv.w * w3.y;
        acc[i].z += hv.x * w0.z + hv.y * w1.z + hv.z * w2.z + hv.w * w3.z;
        acc[i].w += hv.x * w0.w + hv.y * w1.w + hv.z * w2.w + hv.w * w3.w;
      }
    }
    __syncthreads();
  }
  float4 bv = ((const float4*)bias)[c];
#pragma unroll
  for (int i = 0; i < 8; i++) {
    int row = rowBase + rg + 8 * i;
    if (row < N) {
      float4 o = make_float4(acc[i].x + bv.x, acc[i].y + bv.y,
                             acc[i].z + bv.z, acc[i].w + bv.w);
      ((float4*)(out + (size_t)row * H))[c] = o;
    }
  }
}

// ============================ GCN gather-aggregate ============================
// out[n] = relu( sum_{i in [offs[n],offs[n+1])} valP[i] * hw[dstP[i]] )
__global__ __launch_bounds__(256) void k_gcn_gather(
    const float* __restrict__ hw, const int* __restrict__ offs,
    const int* __restrict__ dstP, const float* __restrict__ valP,
    float* __restrict__ out, int N) {
  int n = blockIdx.x * 8 + (threadIdx.x >> 5);
  if (n >= N) return;
  int c = threadIdx.x & 31;
  int s = offs[n], t = offs[n + 1];
  float4 acc = make_float4(0.f, 0.f, 0.f, 0.f);
  for (int i = s; i < t; i++) {
    int d = dstP[i];
    float v = valP[i];
    float4 hv = ((const float4*)(hw + (size_t)d * H))[c];
    acc.x += v * hv.x; acc.y += v * hv.y;
    acc.z += v * hv.z; acc.w += v * hv.w;
  }
  float4 o = make_float4(fmaxf(acc.x, 0.f), fmaxf(acc.y, 0.f),
                         fmaxf(acc.z, 0.f), fmaxf(acc.w, 0.f));
  ((float4*)(out + (size_t)n * H))[c] = o;
}

// ============================ pool (batch is sorted) ============================
// gstart[g] = first node n with batch[n] >= g;  gstart[G] = N
__global__ __launch_bounds__(256) void k_gbounds(
    const int* __restrict__ batch, int* __restrict__ gstart, int N, int G) {
  int n = blockIdx.x * 256 + threadIdx.x;
  if (n > N) return;
  if (n == 0) {
    for (int g = 0; g <= batch[0]; g++) gstart[g] = 0;
  } else if (n == N) {
    for (int g = batch[N - 1] + 1; g <= G; g++) gstart[g] = N;
  } else {
    int b0 = batch[n - 1], b1 = batch[n];
    for (int g = b0 + 1; g <= b1; g++) gstart[g] = n;
  }
}

__global__ __launch_bounds__(128) void k_pool_seg(
    const float* __restrict__ h, const int* __restrict__ gstart,
    float* __restrict__ fp, int G) {
  int g = blockIdx.x;
  int j = threadIdx.x;
  int s = gstart[g], t = gstart[g + 1];
  float acc = 0.f;
  for (int n = s; n < t; n++) acc += h[(size_t)n * H + j];
  fp[(size_t)g * H + j] = acc;
}

// ============================ predictor ============================
__global__ __launch_bounds__(128) void k_pred(
    const float* __restrict__ fp, const float* __restrict__ Wp1,
    const float* __restrict__ bp1, const float* __restrict__ Wp2,
    const float* __restrict__ bp2, float* __restrict__ out, int G) {
  __shared__ float fs[H];
  __shared__ float partial[2];
  int g = blockIdx.x;
  int j = threadIdx.x;
  fs[j] = fp[(size_t)g * H + j];
  __syncthreads();
  float acc = bp1[j];
#pragma unroll 4
  for (int k = 0; k < H; k++) acc += fs[k] * Wp1[(size_t)k * H + j];
  float z = fmaxf(acc, 0.f) * Wp2[j];
#pragma unroll
  for (int off = 32; off > 0; off >>= 1) z += __shfl_down(z, off, 64);
  if ((j & 63) == 0) partial[j >> 6] = z;
  __syncthreads();
  if (j == 0) out[g] = partial[0] + partial[1] + bp2[0];
}

// ============================ launch ============================
extern "C" void kernel_launch(void* const* d_in, const int* in_sizes, int n_in,
                              void* d_out, int out_size, void* d_ws, size_t ws_size,
                              hipStream_t stream) {
  const float* node_attr  = (const float*)d_in[0];
  const float* edge_attr  = (const float*)d_in[1];
  const int*   edge_index = (const int*)d_in[2];
  const int*   adj_index  = (const int*)d_in[3];
  const float* adj_value  = (const float*)d_in[4];
  const int*   batch      = (const int*)d_in[5];
  const float* W_node  = (const float*)d_in[6];
  const float* W_edge  = (const float*)d_in[7];
  const float* b_embed = (const float*)d_in[8];
  const float* W1 = (const float*)d_in[9];
  const float* b1 = (const float*)d_in[10];
  const float* W2 = (const float*)d_in[11];
  const float* b2 = (const float*)d_in[12];
  const float* W3 = (const float*)d_in[13];
  const float* b3 = (const float*)d_in[14];
  const float* Wp1 = (const float*)d_in[15];
  const float* bp1 = (const float*)d_in[16];
  const float* Wp2 = (const float*)d_in[17];
  const float* bp2 = (const float*)d_in[18];
  float* out = (float*)d_out;

  const int E = in_sizes[4];   // 1,600,000
  const int N = in_sizes[5];   // 100,000
  const int G = out_size;      // 2048
  const int NB = (N + 1023) / 1024;   // scan blocks (=98)

  // ---- workspace layout (~120 MB) ----
  float* A     = (float*)d_ws;                    // N*H
  float* B     = A + (size_t)N * H;               // N*H
  float* agg8  = B + (size_t)N * H;               // N*FE
  float* fpool = agg8 + (size_t)N * FE;           // G*H
  float* valP  = fpool + (size_t)G * H;           // E
  int*   dstP  = (int*)(valP + E);                // E (reused as perm for embed)
  int*   cnt   = dstP + E;                        // N
  int*   offs  = cnt + N;                         // N+1
  int*   cursor= offs + N + 1;                    // N
  int*   bsum  = cursor + N;                      // NB
  int*   bsumEx= bsum + NB;                       // NB
  int*   gstart= bsumEx + NB;                     // G+1

  int eb = (E + 255) / 256;
  int gemm_blocks = (N + 63) / 64;

  // ---- sort 1: edges by dst (edge_index row 1) -> perm in dstP ----
  hipMemsetAsync(cnt, 0, (size_t)N * sizeof(int), stream);
  k_hist<<<eb, 256, 0, stream>>>(edge_index + E, cnt, E);
  k_scan1<<<NB, 256, 0, stream>>>(cnt, bsum, N);
  k_scan2<<<1, 128, 0, stream>>>(bsum, bsumEx, offs, NB, N);
  k_scan3<<<NB, 256, 0, stream>>>(cnt, bsumEx, offs, N);
  hipMemcpyAsync(cursor, offs, (size_t)N * sizeof(int), hipMemcpyDeviceToDevice, stream);
  k_scatter_idx<<<eb, 256, 0, stream>>>(edge_index + E, cursor, dstP, E);

  // ---- embed: agg8 then h = relu(node_attr@Wn + agg8@We + b) -> B ----
  k_embed_gather<<<(N + 31) / 32, 256, 0, stream>>>(edge_attr, offs, dstP, agg8, N);
  k_embed_h<<<4096, 256, 0, stream>>>(node_attr, W_node, W_edge, b_embed, agg8, B, N);

  // ---- sort 2: adj by src, payload (dst,val) permuted ----
  hipMemsetAsync(cnt, 0, (size_t)N * sizeof(int), stream);
  k_hist<<<eb, 256, 0, stream>>>(adj_index, cnt, E);
  k_scan1<<<NB, 256, 0, stream>>>(cnt, bsum, N);
  k_scan2<<<1, 128, 0, stream>>>(bsum, bsumEx, offs, NB, N);
  k_scan3<<<NB, 256, 0, stream>>>(cnt, bsumEx, offs, N);
  hipMemcpyAsync(cursor, offs, (size_t)N * sizeof(int), hipMemcpyDeviceToDevice, stream);
  k_scatter_pay<<<eb, 256, 0, stream>>>(adj_index, adj_index + E, adj_value,
                                        cursor, dstP, valP, E);

  // ---- graph bounds for pool (independent) ----
  k_gbounds<<<(N + 256) / 256, 256, 0, stream>>>(batch, gstart, N, G);

  // ---- 3 GCN layers: A = B@W+b ; B = relu(gather(A)) ----
  int agb = (N + 7) / 8;
  k_gemm<<<gemm_blocks, 256, 0, stream>>>(B, W1, b1, A, N);
  k_gcn_gather<<<agb, 256, 0, stream>>>(A, offs, dstP, valP, B, N);
  k_gemm<<<gemm_blocks, 256, 0, stream>>>(B, W2, b2, A, N);
  k_gcn_gather<<<agb, 256, 0, stream>>>(A, offs, dstP, valP, B, N);
  k_gemm<<<gemm_blocks, 256, 0, stream>>>(B, W3, b3, A, N);
  k_gcn_gather<<<agb, 256, 0, stream>>>(A, offs, dstP, valP, B, N);

  // ---- pool + predictor ----
  k_pool_seg<<<G, 128, 0, stream>>>(B, gstart, fpool, G);
  k_pred<<<G, 128, 0, stream>>>(fpool, Wp1, bp1, Wp2, bp2, out, G);
}